// Round 9
// baseline (675.586 us; speedup 1.0000x reference)
//
#include <hip/hip_runtime.h>
#include <hip/hip_cooperative_groups.h>

namespace cg = cooperative_groups;

#define NTOT 2048
#define INF 64
#define HD 256
#define EHD 128
#define ONF 64
#define NL 4

typedef __attribute__((ext_vector_type(8))) short bf16x8;
typedef __attribute__((ext_vector_type(4))) float f32x4;

__device__ __forceinline__ float silu_f(float v) {
    return v * __builtin_amdgcn_rcpf(1.0f + __expf(-v));
}
__device__ __forceinline__ unsigned short f2bf_rn(float f) {
    unsigned u = __float_as_uint(f);
    u += 0x7FFFu + ((u >> 16) & 1u);
    return (unsigned short)(u >> 16);
}
__device__ __forceinline__ void split_rn(float v, unsigned short& h, unsigned short& l) {
    h = f2bf_rn(v);
    l = f2bf_rn(v - __uint_as_float((unsigned)h << 16));
}
__device__ __forceinline__ void split_tr(float v, unsigned& uh, unsigned& ul) {
    unsigned u = __float_as_uint(v);
    uh = u & 0xffff0000u;
    ul = __float_as_uint(v - __uint_as_float(uh)) & 0xffff0000u;
}
__device__ __forceinline__ float bfraw2f(unsigned short s) {
    return __uint_as_float((unsigned)s << 16);
}

#define MFMA(a, b, c) __builtin_amdgcn_mfma_f32_16x16x32_bf16(a, b, c, 0, 0, 0)

// ===================== ONE cooperative kernel, grid-size agnostic =====================
__global__ __launch_bounds__(512, 4) void k_mega(
        const float* __restrict__ h, const float* __restrict__ w_in,
        const float* __restrict__ b_in, const float* __restrict__ w_out,
        const float* __restrict__ b_out, const float* __restrict__ we1,
        const float* __restrict__ be1, const float* __restrict__ we2,
        const float* __restrict__ be2, const float* __restrict__ wn1,
        const float* __restrict__ bn1, const float* __restrict__ wn2,
        const float* __restrict__ bn2, float* __restrict__ ws,
        float* __restrict__ outp) {
    cg::grid_group gg = cg::this_grid();
    __shared__ __align__(16) char smem[57344];
    const int bid = blockIdx.x;
    const int nb = gridDim.x;
    const int t = threadIdx.x;
    const int w = t >> 6, lane = t & 63;
    const int r0 = (lane >> 4) * 4;

    // workspace partition (elements)
    float* A     = ws;
    float* Bb    = A + 262144;
    float* agg   = Bb + 262144;
    short* xs_hi = (short*)(agg + 262144);
    short* xs_lo = xs_hi + 524288;
    short* hwin  = xs_lo + 524288;
    short* lwin  = hwin + 16384;
    short* hwe1  = lwin + 16384;
    short* lwe1  = hwe1 + 262144;
    short* hwn1  = lwe1 + 262144;
    short* lwn1  = hwn1 + 393216;
    short* hwn2  = lwn1 + 393216;
    short* lwn2  = hwn2 + 262144;
    short* hwout = lwn2 + 262144;
    short* lwout = hwout + 16384;
    short* hwe2  = lwout + 16384;

    // ---------------- P0: weight fragment prep (grid-stride) ----------------
    for (int gid = bid * 512 + t; gid < 126976; gid += nb * 512) {
        const float* src; short* hd; short* ld;
        int sl, dst, KS, N, mode;
        if (gid < 2048)        { sl = gid;             dst = gid; src = w_in;                                  hd = hwin;  ld = lwin;  KS = 2;  N = 256; mode = 0; }
        else if (gid < 34816)  { int g = gid - 2048;   sl = g & 8191;  dst = g; src = we1 + (size_t)(g >> 13) * 512 * 128;   hd = hwe1;  ld = lwe1;  KS = 8;  N = 256; mode = 1; }
        else if (gid < 83968)  { int g = gid - 34816;  sl = g % 12288; dst = g; src = wn1 + (size_t)(g / 12288) * 384 * 256; hd = hwn1;  ld = lwn1;  KS = 12; N = 256; mode = 0; }
        else if (gid < 116736) { int g = gid - 83968;  sl = g & 8191;  dst = g; src = wn2 + (size_t)(g >> 13) * 256 * 256;   hd = hwn2;  ld = lwn2;  KS = 8;  N = 256; mode = 0; }
        else if (gid < 118784) { int g = gid - 116736; sl = g;         dst = g; src = w_out;                                 hd = hwout; ld = lwout; KS = 8;  N = 64;  mode = 0; }
        else                   { int g = gid - 118784; sl = g & 2047;  dst = g; src = we2 + (size_t)(g >> 11) * 128 * 128;   hd = hwe2;  ld = 0;     KS = 4;  N = 128; mode = 0; }
        const int lanep = sl & 63;
        const int t2 = sl >> 6;
        const int ks = t2 % KS;
        const int nt = t2 / KS;
        const int n = nt * 16 + (lanep & 15);
        const int k0 = ks * 32 + ((lanep >> 4) << 3);
        short h8[8], l8[8];
#pragma unroll
        for (int i = 0; i < 8; ++i) {
            int k = k0 + i;
            float f;
            if (mode == 1) f = (n < 128) ? src[(size_t)k * 128 + n] : src[(size_t)(256 + k) * 128 + (n - 128)];
            else           f = src[(size_t)k * N + n];
            unsigned short hh, ll;
            split_rn(f, hh, ll);
            h8[i] = (short)hh; l8[i] = (short)ll;
        }
#pragma unroll
        for (int i = 0; i < 8; ++i) hd[(size_t)dst * 8 + i] = h8[i];
        if (ld) {
#pragma unroll
            for (int i = 0; i < 8; ++i) ld[(size_t)dst * 8 + i] = l8[i];
        }
    }
    gg.sync();

    // ---------------- P1: embed + layer-0 A/B (grid-stride over 128 M-tiles) ----------------
    for (int mt = bid; mt < 128; mt += nb) {
        short (*hls)[2][64][8] = (short(*)[2][64][8])smem;
        short (*xls)[8][64][8] = (short(*)[8][64][8])(smem + 4096);
        const int n0 = mt * 16;
#pragma unroll
        for (int rep = 0; rep < 2; ++rep) {
            int s = rep * 512 + t;
            int m = s >> 6, k = s & 63;
            float v = h[(size_t)(n0 + m) * INF + k];
            unsigned uh, ul;
            split_tr(v, uh, ul);
            int ks = k >> 5, lane2 = m + 16 * ((k & 31) >> 3), i0 = k & 7;
            hls[0][ks][lane2][i0] = (short)(uh >> 16);
            hls[1][ks][lane2][i0] = (short)(ul >> 16);
        }
        __syncthreads();
        f32x4 acc[2];
#pragma unroll
        for (int nti2 = 0; nti2 < 2; ++nti2) {
            const int nt = w * 2 + nti2;
            f32x4 a = {0.f, 0.f, 0.f, 0.f};
#pragma unroll
            for (int ks = 0; ks < 2; ++ks) {
                bf16x8 ah = *(const bf16x8*)&hls[0][ks][lane][0];
                bf16x8 al = *(const bf16x8*)&hls[1][ks][lane][0];
                bf16x8 bh = ((const bf16x8*)hwin)[(nt * 2 + ks) * 64 + lane];
                bf16x8 bl = ((const bf16x8*)lwin)[(nt * 2 + ks) * 64 + lane];
                a = MFMA(ah, bh, a); a = MFMA(al, bh, a); a = MFMA(ah, bl, a);
            }
            acc[nti2] = a;
        }
#pragma unroll
        for (int nti2 = 0; nti2 < 2; ++nti2) {
            int col = (w * 2 + nti2) * 16 + (lane & 15);
            float bias = b_in[col];
            int ks = col >> 5, l2b = 16 * ((col & 31) >> 3), i2 = col & 7;
#pragma unroll
            for (int reg = 0; reg < 4; ++reg) {
                float xv = acc[nti2][reg] + bias;
                unsigned uh, ul;
                split_tr(xv, uh, ul);
                xls[0][ks][r0 + reg + l2b][i2] = (short)(uh >> 16);
                xls[1][ks][r0 + reg + l2b][i2] = (short)(ul >> 16);
            }
        }
        __syncthreads();
#pragma unroll
        for (int rep = 0; rep < 2; ++rep) {
            int s = rep * 512 + t;
            int plane = s >> 9, ks = (s >> 6) & 7, ln = s & 63;
            bf16x8 v = *(const bf16x8*)&xls[plane][ks][ln][0];
            bf16x8* dstp = (bf16x8*)(plane ? xs_lo : xs_hi);
            dstp[(size_t)(mt * 8 + ks) * 64 + ln] = v;
        }
#pragma unroll
        for (int nti2 = 0; nti2 < 2; ++nti2) {
            const int nt = w * 2 + nti2;
            f32x4 a = {0.f, 0.f, 0.f, 0.f};
#pragma unroll
            for (int ks = 0; ks < 8; ++ks) {
                bf16x8 ah = *(const bf16x8*)&xls[0][ks][lane][0];
                bf16x8 al = *(const bf16x8*)&xls[1][ks][lane][0];
                bf16x8 bh = ((const bf16x8*)hwe1)[(nt * 8 + ks) * 64 + lane];
                bf16x8 bl = ((const bf16x8*)lwe1)[(nt * 8 + ks) * 64 + lane];
                a = MFMA(ah, bh, a); a = MFMA(al, bh, a); a = MFMA(ah, bl, a);
            }
            int j = nt * 16 + (lane & 15);
            float bias = (j < 128) ? be1[j] : 0.0f;
            float* dstp = (j < 128) ? A : Bb;
            int jj = j & 127;
#pragma unroll
            for (int reg = 0; reg < 4; ++reg)
                dstp[(size_t)(n0 + r0 + reg) * 128 + jj] = a[reg] + bias;
        }
        __syncthreads();
    }
    gg.sync();

    for (int l = 0; l < NL; ++l) {
        // ---------------- P2: edge (grid-stride over 2048 receivers) ----------------
        {
            short (*fr)[2][4][64][8] = (short(*)[2][4][64][8])smem;
            float (*red)[4][2][16]   = (float(*)[4][2][16])(smem + 32768);
            const short* hwe2l = hwe2 + (size_t)l * 2048 * 8;
            const int sh = w >> 2, jt = w & 3;
            const int ko = t & 15;
            const int ksw = ko >> 2;
            const int lfbase = (ko & 3) << 4;
            const int mtl_s = (t >> 8) & 1;
            const int c15 = (t >> 4) & 15;
            bf16x8 bh2[2][4];
#pragma unroll
            for (int nti = 0; nti < 2; ++nti)
#pragma unroll
                for (int ks = 0; ks < 4; ++ks)
                    bh2[nti][ks] = ((const bf16x8*)hwe2l)[((jt * 2 + nti) * 4 + ks) * 64 + lane];
            float be2v[2];
#pragma unroll
            for (int nti = 0; nti < 2; ++nti)
                be2v[nti] = be2[l * EHD + (jt * 2 + nti) * 16 + (lane & 15)];

            for (int n = bid; n < NTOT; n += nb) {
                const int b0 = n & ~127, r = n & 127;
                const float4 av0 = *(const float4*)&A[(size_t)n * EHD + ko * 8];
                const float4 av1 = *(const float4*)&A[(size_t)n * EHD + ko * 8 + 4];
#pragma unroll
                for (int i = 0; i < 4; ++i) {
                    const int c = i * 32 + (t >> 4);
                    const float4 bv0 = *(const float4*)&Bb[(size_t)(b0 + c) * EHD + ko * 8];
                    const float4 bv1 = *(const float4*)&Bb[(size_t)(b0 + c) * EHD + ko * 8 + 4];
                    float v[8] = {bv0.x + av0.x, bv0.y + av0.y, bv0.z + av0.z, bv0.w + av0.w,
                                  bv1.x + av1.x, bv1.y + av1.y, bv1.z + av1.z, bv1.w + av1.w};
                    unsigned short rb[8];
#pragma unroll
                    for (int j = 0; j < 8; ++j) rb[j] = f2bf_rn(silu_f(v[j]));
                    uint4 ph;
                    ph.x = (unsigned)rb[0] | ((unsigned)rb[1] << 16);
                    ph.y = (unsigned)rb[2] | ((unsigned)rb[3] << 16);
                    ph.z = (unsigned)rb[4] | ((unsigned)rb[5] << 16);
                    ph.w = (unsigned)rb[6] | ((unsigned)rb[7] << 16);
                    const int lf = c15 | lfbase;
                    *(uint4*)&fr[i][mtl_s][ksw][lf ^ (ksw << 1)][0] = ph;
                }
                __syncthreads();
                float colsum[2] = {0.0f, 0.0f};
#pragma unroll
                for (int chl = 0; chl < 2; ++chl) {
                    const int ch = sh * 2 + chl;
#pragma unroll
                    for (int mtl = 0; mtl < 2; ++mtl) {
                        bf16x8 ah[4];
#pragma unroll
                        for (int ks = 0; ks < 4; ++ks)
                            ah[ks] = *(const bf16x8*)&fr[ch][mtl][ks][lane ^ (ks << 1)][0];
                        const int cbase = ch * 32 + mtl * 16 + ((lane >> 4) << 2);
#pragma unroll
                        for (int nti = 0; nti < 2; ++nti) {
                            f32x4 a = {0.0f, 0.0f, 0.0f, 0.0f};
#pragma unroll
                            for (int ks = 0; ks < 4; ++ks)
                                a = MFMA(ah[ks], bh2[nti][ks], a);
#pragma unroll
                            for (int reg = 0; reg < 4; ++reg) {
                                const int c = cbase + reg;
                                float s = silu_f(a[reg] + be2v[nti]);
                                colsum[nti] += (c != r) ? s : 0.0f;
                            }
                        }
                    }
                }
#pragma unroll
                for (int nti = 0; nti < 2; ++nti) {
                    float s = colsum[nti];
                    s += __shfl_xor(s, 16);
                    s += __shfl_xor(s, 32);
                    if (lane < 16) red[sh][jt][nti][lane] = s;
                }
                __syncthreads();
                if (t < 128) {
                    const int jtf = t >> 5, ntif = (t >> 4) & 1, j16 = t & 15;
                    agg[(size_t)n * EHD + jtf * 32 + ntif * 16 + j16] =
                        red[0][jtf][ntif][j16] + red[1][jtf][ntif][j16];
                }
                __syncthreads();
            }
        }
        gg.sync();

        // ---------------- P3: node MLP + residual + next A/B (or out) ----------------
        const int last = (l == NL - 1);
        for (int mt = bid; mt < 128; mt += nb) {
            short (*cat)[12][64][8] = (short(*)[12][64][8])smem;
            short (*u1x)[8][64][8]  = (short(*)[8][64][8])(smem + 24576);
            short (*xnx)[8][64][8]  = (short(*)[8][64][8])(smem + 40960);
            const short* hwn1l = hwn1 + (size_t)l * 12288 * 8;
            const short* lwn1l = lwn1 + (size_t)l * 12288 * 8;
            const short* hwn2l = hwn2 + (size_t)l * 8192 * 8;
            const short* lwn2l = lwn2 + (size_t)l * 8192 * 8;
            const int lp = last ? 0 : (l + 1);
            const short* hwe1n = hwe1 + (size_t)lp * 8192 * 8;
            const short* lwe1n = lwe1 + (size_t)lp * 8192 * 8;
            const int n0 = mt * 16;
#pragma unroll
            for (int rep = 0; rep < 2; ++rep) {
                int s = rep * 512 + t;
                int plane = s >> 9, ks = (s >> 6) & 7, ln = s & 63;
                const bf16x8* srcp = (const bf16x8*)(plane ? xs_lo : xs_hi);
                *(bf16x8*)&cat[plane][ks][ln][0] = srcp[(size_t)(mt * 8 + ks) * 64 + ln];
            }
            {
                const int m = t >> 5, kq = t & 31, k0 = kq * 4;
                const float4 v4 = *(const float4*)&agg[(size_t)(n0 + m) * EHD + k0];
                unsigned uh0, ul0, uh1, ul1, uh2, ul2, uh3, ul3;
                split_tr(v4.x, uh0, ul0); split_tr(v4.y, uh1, ul1);
                split_tr(v4.z, uh2, ul2); split_tr(v4.w, uh3, ul3);
                const int ks = 8 + (k0 >> 5);
                const int lane2 = m + 16 * ((k0 & 31) >> 3);
                const int i0 = k0 & 7;
                *(uint2*)&cat[0][ks][lane2][i0] = make_uint2((uh0 >> 16) | uh1, (uh2 >> 16) | uh3);
                *(uint2*)&cat[1][ks][lane2][i0] = make_uint2((ul0 >> 16) | ul1, (ul2 >> 16) | ul3);
            }
            __syncthreads();
            f32x4 acc1[2];
#pragma unroll
            for (int nti2 = 0; nti2 < 2; ++nti2) {
                const int nt = w * 2 + nti2;
                f32x4 a = {0.f, 0.f, 0.f, 0.f};
#pragma unroll
                for (int ks = 0; ks < 12; ++ks) {
                    bf16x8 ah = *(const bf16x8*)&cat[0][ks][lane][0];
                    bf16x8 al = *(const bf16x8*)&cat[1][ks][lane][0];
                    bf16x8 bh = ((const bf16x8*)hwn1l)[(nt * 12 + ks) * 64 + lane];
                    bf16x8 bl = ((const bf16x8*)lwn1l)[(nt * 12 + ks) * 64 + lane];
                    a = MFMA(ah, bh, a); a = MFMA(al, bh, a); a = MFMA(ah, bl, a);
                }
                acc1[nti2] = a;
            }
#pragma unroll
            for (int nti2 = 0; nti2 < 2; ++nti2) {
                const int col = (w * 2 + nti2) * 16 + (lane & 15);
                const int ksu = col >> 5, l2b = 16 * ((col & 31) >> 3), i2 = col & 7;
                float bias = bn1[l * HD + col];
#pragma unroll
                for (int reg = 0; reg < 4; ++reg) {
                    float uv = silu_f(acc1[nti2][reg] + bias);
                    unsigned uh, ul;
                    split_tr(uv, uh, ul);
                    u1x[0][ksu][r0 + reg + l2b][i2] = (short)(uh >> 16);
                    u1x[1][ksu][r0 + reg + l2b][i2] = (short)(ul >> 16);
                }
            }
            __syncthreads();
            f32x4 acc2[2];
#pragma unroll
            for (int nti2 = 0; nti2 < 2; ++nti2) {
                const int nt = w * 2 + nti2;
                f32x4 a = {0.f, 0.f, 0.f, 0.f};
#pragma unroll
                for (int ks = 0; ks < 8; ++ks) {
                    bf16x8 ah = *(const bf16x8*)&u1x[0][ks][lane][0];
                    bf16x8 al = *(const bf16x8*)&u1x[1][ks][lane][0];
                    bf16x8 bh = ((const bf16x8*)hwn2l)[(nt * 8 + ks) * 64 + lane];
                    bf16x8 bl = ((const bf16x8*)lwn2l)[(nt * 8 + ks) * 64 + lane];
                    a = MFMA(ah, bh, a); a = MFMA(al, bh, a); a = MFMA(ah, bl, a);
                }
                acc2[nti2] = a;
            }
#pragma unroll
            for (int nti2 = 0; nti2 < 2; ++nti2) {
                const int col = (w * 2 + nti2) * 16 + (lane & 15);
                const int ksu = col >> 5, l2b = 16 * ((col & 31) >> 3), i2 = col & 7;
                float bias = bn2[l * HD + col];
#pragma unroll
                for (int reg = 0; reg < 4; ++reg) {
                    int lane2 = r0 + reg + l2b;
                    float xold = bfraw2f((unsigned short)cat[0][ksu][lane2][i2])
                               + bfraw2f((unsigned short)cat[1][ksu][lane2][i2]);
                    float xv = acc2[nti2][reg] + bias + xold;
                    unsigned uh, ul;
                    split_tr(xv, uh, ul);
                    xnx[0][ksu][lane2][i2] = (short)(uh >> 16);
                    xnx[1][ksu][lane2][i2] = (short)(ul >> 16);
                }
            }
            __syncthreads();
            if (!last) {
#pragma unroll
                for (int rep = 0; rep < 2; ++rep) {
                    int s = rep * 512 + t;
                    int plane = s >> 9, ks = (s >> 6) & 7, ln = s & 63;
                    bf16x8 v = *(const bf16x8*)&xnx[plane][ks][ln][0];
                    bf16x8* dstp = (bf16x8*)(plane ? xs_lo : xs_hi);
                    dstp[(size_t)(mt * 8 + ks) * 64 + ln] = v;
                }
#pragma unroll
                for (int nti2 = 0; nti2 < 2; ++nti2) {
                    const int nt = w * 2 + nti2;
                    f32x4 a = {0.f, 0.f, 0.f, 0.f};
#pragma unroll
                    for (int ks = 0; ks < 8; ++ks) {
                        bf16x8 ah = *(const bf16x8*)&xnx[0][ks][lane][0];
                        bf16x8 al = *(const bf16x8*)&xnx[1][ks][lane][0];
                        bf16x8 bh = ((const bf16x8*)hwe1n)[(nt * 8 + ks) * 64 + lane];
                        bf16x8 bl = ((const bf16x8*)lwe1n)[(nt * 8 + ks) * 64 + lane];
                        a = MFMA(ah, bh, a); a = MFMA(al, bh, a); a = MFMA(ah, bl, a);
                    }
                    int j = nt * 16 + (lane & 15);
                    float bias = (j < 128) ? be1[lp * EHD + j] : 0.0f;
                    float* dstp = (j < 128) ? A : Bb;
                    int jj = j & 127;
#pragma unroll
                    for (int reg = 0; reg < 4; ++reg)
                        dstp[(size_t)(n0 + r0 + reg) * 128 + jj] = a[reg] + bias;
                }
            } else if (w < 4) {
                f32x4 a = {0.f, 0.f, 0.f, 0.f};
#pragma unroll
                for (int ks = 0; ks < 8; ++ks) {
                    bf16x8 ah = *(const bf16x8*)&xnx[0][ks][lane][0];
                    bf16x8 al = *(const bf16x8*)&xnx[1][ks][lane][0];
                    bf16x8 bh = ((const bf16x8*)hwout)[(w * 8 + ks) * 64 + lane];
                    bf16x8 bl = ((const bf16x8*)lwout)[(w * 8 + ks) * 64 + lane];
                    a = MFMA(ah, bh, a); a = MFMA(al, bh, a); a = MFMA(ah, bl, a);
                }
                int col = w * 16 + (lane & 15);
                float bias = b_out[col];
#pragma unroll
                for (int reg = 0; reg < 4; ++reg)
                    outp[(size_t)(n0 + r0 + reg) * ONF + col] = a[reg] + bias;
            }
            __syncthreads();
        }
        if (!last) gg.sync();
    }
}

extern "C" void kernel_launch(void* const* d_in, const int* in_sizes, int n_in,
                              void* d_out, int out_size, void* d_ws, size_t ws_size,
                              hipStream_t stream) {
    const float* h     = (const float*)d_in[0];
    const float* w_in  = (const float*)d_in[3];
    const float* b_in  = (const float*)d_in[4];
    const float* w_out = (const float*)d_in[5];
    const float* b_out = (const float*)d_in[6];
    const float* we1   = (const float*)d_in[7];
    const float* be1   = (const float*)d_in[8];
    const float* we2   = (const float*)d_in[9];
    const float* be2   = (const float*)d_in[10];
    const float* wn1   = (const float*)d_in[11];
    const float* bn1   = (const float*)d_in[12];
    const float* wn2   = (const float*)d_in[13];
    const float* bn2   = (const float*)d_in[14];
    float* ws   = (float*)d_ws;
    float* outp = (float*)d_out;

    // Size the cooperative grid from actual achievable occupancy (host query, capture-safe).
    int blocksPerCU = 0;
    hipError_t qerr = hipOccupancyMaxActiveBlocksPerMultiprocessor(
        &blocksPerCU, (const void*)k_mega, 512, 0);
    if (qerr != hipSuccess || blocksPerCU < 1) blocksPerCU = 1;
    int grid = blocksPerCU * 256;
    if (grid > 512) grid = 512;

    void* kargs[] = {
        (void*)&h, (void*)&w_in, (void*)&b_in, (void*)&w_out, (void*)&b_out,
        (void*)&we1, (void*)&be1, (void*)&we2, (void*)&be2,
        (void*)&wn1, (void*)&bn1, (void*)&wn2, (void*)&bn2,
        (void*)&ws, (void*)&outp
    };
    hipLaunchCooperativeKernel((const void*)k_mega, dim3(grid), dim3(512),
                               kargs, 0, stream);
}

// Round 10
// 165.963 us; speedup vs baseline: 4.0707x; 4.0707x over previous
//
#include <hip/hip_runtime.h>
#include <hip/hip_bf16.h>

#define NTOT 2048
#define INF 64
#define HD 256
#define EHD 128
#define ONF 64
#define NL 4

typedef __attribute__((ext_vector_type(8))) short bf16x8;
typedef __attribute__((ext_vector_type(4))) float f32x4;

__device__ __forceinline__ float silu_f(float v) {
    return v * __builtin_amdgcn_rcpf(1.0f + __expf(-v));
}

// HW-packed bf16 pair (compiler emits v_cvt_pk_bf16_f32)
__device__ __forceinline__ unsigned pk_bf16(float a, float b) {
    __hip_bfloat162 p = __float22bfloat162_rn(float2{a, b});
    return *(unsigned*)&p;
}

// rounded bf16 (weights, one-time prep)
__device__ __forceinline__ unsigned short f2bf_rn(float f) {
    unsigned u = __float_as_uint(f);
    u += 0x7FFFu + ((u >> 16) & 1u);
    return (unsigned short)(u >> 16);
}
__device__ __forceinline__ void split_rn(float v, unsigned short& h, unsigned short& l) {
    h = f2bf_rn(v);
    l = f2bf_rn(v - __uint_as_float((unsigned)h << 16));
}
// truncating split (activations)
__device__ __forceinline__ void split_tr(float v, unsigned& uh, unsigned& ul) {
    unsigned u = __float_as_uint(v);
    uh = u & 0xffff0000u;
    ul = __float_as_uint(v - __uint_as_float(uh)) & 0xffff0000u;
}
__device__ __forceinline__ float bfraw2f(unsigned short s) {
    return __uint_as_float((unsigned)s << 16);
}

// ================= weight fragment prep =================
__global__ __launch_bounds__(256) void k_prep(
        const float* __restrict__ w_in, const float* __restrict__ we1,
        const float* __restrict__ wn1, const float* __restrict__ wn2,
        const float* __restrict__ w_out, const float* __restrict__ we2,
        short* __restrict__ hwin, short* __restrict__ lwin,
        short* __restrict__ hwe1, short* __restrict__ lwe1,
        short* __restrict__ hwn1, short* __restrict__ lwn1,
        short* __restrict__ hwn2, short* __restrict__ lwn2,
        short* __restrict__ hwout, short* __restrict__ lwout,
        short* __restrict__ hwe2) {
    const int gid = blockIdx.x * 256 + threadIdx.x;
    const float* src; short* hd; short* ld;
    int sl, dst, KS, N, mode;
    if (gid < 2048)        { sl = gid;                dst = gid;           src = w_in;                                  hd = hwin;  ld = lwin;  KS = 2;  N = 256; mode = 0; }
    else if (gid < 34816)  { int g = gid - 2048;      sl = g & 8191;  dst = g; src = we1 + (size_t)(g >> 13) * 512 * 128;   hd = hwe1;  ld = lwe1;  KS = 8;  N = 256; mode = 1; }
    else if (gid < 83968)  { int g = gid - 34816;     sl = g % 12288; dst = g; src = wn1 + (size_t)(g / 12288) * 384 * 256; hd = hwn1;  ld = lwn1;  KS = 12; N = 256; mode = 0; }
    else if (gid < 116736) { int g = gid - 83968;     sl = g & 8191;  dst = g; src = wn2 + (size_t)(g >> 13) * 256 * 256;   hd = hwn2;  ld = lwn2;  KS = 8;  N = 256; mode = 0; }
    else if (gid < 118784) { int g = gid - 116736;    sl = g;         dst = g; src = w_out;                                 hd = hwout; ld = lwout; KS = 8;  N = 64;  mode = 0; }
    else if (gid < 126976) { int g = gid - 118784;    sl = g & 2047;  dst = g; src = we2 + (size_t)(g >> 11) * 128 * 128;   hd = hwe2;  ld = 0;     KS = 4;  N = 128; mode = 0; }
    else return;
    const int lane = sl & 63;
    const int t2 = sl >> 6;
    const int ks = t2 % KS;
    const int nt = t2 / KS;
    const int n = nt * 16 + (lane & 15);
    const int k0 = ks * 32 + ((lane >> 4) << 3);
    short h8[8], l8[8];
#pragma unroll
    for (int i = 0; i < 8; ++i) {
        int k = k0 + i;
        float f;
        if (mode == 1) f = (n < 128) ? src[(size_t)k * 128 + n] : src[(size_t)(256 + k) * 128 + (n - 128)];
        else           f = src[(size_t)k * N + n];
        unsigned short hh, ll;
        split_rn(f, hh, ll);
        h8[i] = (short)hh; l8[i] = (short)ll;
    }
#pragma unroll
    for (int i = 0; i < 8; ++i) hd[(size_t)dst * 8 + i] = h8[i];
    if (ld) {
#pragma unroll
        for (int i = 0; i < 8; ++i) ld[(size_t)dst * 8 + i] = l8[i];
    }
}

// ================= embed + layer-0 A/B (1024 thr / 16 waves) =================
__global__ __launch_bounds__(1024, 4) void k_embed_ab(
        const float* __restrict__ h, const float* __restrict__ b_in,
        const float* __restrict__ be1,
        const short* __restrict__ hwin, const short* __restrict__ lwin,
        const short* __restrict__ hwe1, const short* __restrict__ lwe1,
        short* __restrict__ xs_hi, short* __restrict__ xs_lo,
        float* __restrict__ A, float* __restrict__ Bb) {
    __shared__ __align__(16) short hls[2][2][64][8];
    __shared__ __align__(16) short xls[2][8][64][8];
    const int t = threadIdx.x;
    const int mt = blockIdx.x;
    const int n0 = mt * 16;
    const int w = t >> 6, lane = t & 63;
    const int r0 = (lane >> 4) * 4;

    {
        const int m = t >> 6, k = t & 63;
        float v = h[(size_t)(n0 + m) * INF + k];
        unsigned uh, ul;
        split_tr(v, uh, ul);
        const int ks = k >> 5;
        const int lane2 = m + 16 * ((k & 31) >> 3);
        const int i0 = k & 7;
        hls[0][ks][lane2][i0] = (short)(uh >> 16);
        hls[1][ks][lane2][i0] = (short)(ul >> 16);
    }
    __syncthreads();
    f32x4 acc = {0.f, 0.f, 0.f, 0.f};
#pragma unroll
    for (int ks = 0; ks < 2; ++ks) {
        bf16x8 ah = *(const bf16x8*)&hls[0][ks][lane][0];
        bf16x8 al = *(const bf16x8*)&hls[1][ks][lane][0];
        bf16x8 bh = ((const bf16x8*)hwin)[(w * 2 + ks) * 64 + lane];
        bf16x8 bl = ((const bf16x8*)lwin)[(w * 2 + ks) * 64 + lane];
        acc = __builtin_amdgcn_mfma_f32_16x16x32_bf16(ah, bh, acc, 0, 0, 0);
        acc = __builtin_amdgcn_mfma_f32_16x16x32_bf16(al, bh, acc, 0, 0, 0);
        acc = __builtin_amdgcn_mfma_f32_16x16x32_bf16(ah, bl, acc, 0, 0, 0);
    }
    {
        int col = w * 16 + (lane & 15);
        float bias = b_in[col];
        int ks = col >> 5, l2b = 16 * ((col & 31) >> 3), i2 = col & 7;
#pragma unroll
        for (int reg = 0; reg < 4; ++reg) {
            float xv = acc[reg] + bias;
            unsigned uh, ul;
            split_tr(xv, uh, ul);
            xls[0][ks][r0 + reg + l2b][i2] = (short)(uh >> 16);
            xls[1][ks][r0 + reg + l2b][i2] = (short)(ul >> 16);
        }
    }
    __syncthreads();
    {
        int s = t;
        int plane = s >> 9, ks = (s >> 6) & 7, ln = s & 63;
        bf16x8 v = *(const bf16x8*)&xls[plane][ks][ln][0];
        bf16x8* dstp = (bf16x8*)(plane ? xs_lo : xs_hi);
        dstp[(size_t)(mt * 8 + ks) * 64 + ln] = v;
    }
    f32x4 acc1 = {0.f, 0.f, 0.f, 0.f};
#pragma unroll
    for (int ks = 0; ks < 8; ++ks) {
        bf16x8 ah = *(const bf16x8*)&xls[0][ks][lane][0];
        bf16x8 al = *(const bf16x8*)&xls[1][ks][lane][0];
        bf16x8 bh = ((const bf16x8*)hwe1)[(w * 8 + ks) * 64 + lane];
        bf16x8 bl = ((const bf16x8*)lwe1)[(w * 8 + ks) * 64 + lane];
        acc1 = __builtin_amdgcn_mfma_f32_16x16x32_bf16(ah, bh, acc1, 0, 0, 0);
        acc1 = __builtin_amdgcn_mfma_f32_16x16x32_bf16(al, bh, acc1, 0, 0, 0);
        acc1 = __builtin_amdgcn_mfma_f32_16x16x32_bf16(ah, bl, acc1, 0, 0, 0);
    }
    {
        int j = w * 16 + (lane & 15);
        float bias = (j < 128) ? be1[j] : 0.0f;
        float* dstp = (j < 128) ? A : Bb;
        int jj = j & 127;
#pragma unroll
        for (int reg = 0; reg < 4; ++reg) {
            int node = n0 + r0 + reg;
            dstp[(size_t)node * 128 + jj] = acc1[reg] + bias;
        }
    }
}

// ================= edge GEMM + scatter-sum, single-bf16 MFMA, software-pipelined =================
__global__ __launch_bounds__(256, 4) void k_edge_mfma(
        const float* __restrict__ A, const float* __restrict__ Bb,
        const short* __restrict__ hwe2,
        const float* __restrict__ be2, float* __restrict__ agg) {
    __shared__ __align__(16) short fr[2][2][4][64][8];  // [buf][mt][ks][lane][i] rounded bf16
    const int n = blockIdx.x;
    const int b0 = n & ~127;
    const int r = n & 127;
    const int t = threadIdx.x;
    const int w = t >> 6;
    const int lane = t & 63;
    const int kg = t & 15;
    const int ksw = kg >> 2;
    const int lanef = ((kg & 3) << 4);

    float a8[8];
    {
        const float4 a0 = *(const float4*)&A[(size_t)n * EHD + kg * 8];
        const float4 a1 = *(const float4*)&A[(size_t)n * EHD + kg * 8 + 4];
        a8[0] = a0.x; a8[1] = a0.y; a8[2] = a0.z; a8[3] = a0.w;
        a8[4] = a1.x; a8[5] = a1.y; a8[6] = a1.z; a8[7] = a1.w;
    }
    bf16x8 bh[2][4];
#pragma unroll
    for (int nti = 0; nti < 2; ++nti) {
        const int nt = w * 2 + nti;
#pragma unroll
        for (int ks = 0; ks < 4; ++ks)
            bh[nti][ks] = ((const bf16x8*)hwe2)[(nt * 4 + ks) * 64 + lane];
    }
    float be2v[2];
#pragma unroll
    for (int nti = 0; nti < 2; ++nti)
        be2v[nti] = be2[(w * 2 + nti) * 16 + (lane & 15)];

    float colsum[2] = {0.0f, 0.0f};

    // prologue: stage chunk 0 into buf 0
#pragma unroll
    for (int iter = 0; iter < 2; ++iter) {
        const int c_l = iter * 16 + (t >> 4);
        const int mtl = c_l >> 4;
        const float* Brow = &Bb[(size_t)(b0 + c_l) * EHD + kg * 8];
        const float4 bv0 = *(const float4*)Brow;
        const float4 bv1 = *(const float4*)(Brow + 4);
        float s0 = silu_f(bv0.x + a8[0]), s1 = silu_f(bv0.y + a8[1]);
        float s2 = silu_f(bv0.z + a8[2]), s3 = silu_f(bv0.w + a8[3]);
        float s4 = silu_f(bv1.x + a8[4]), s5 = silu_f(bv1.y + a8[5]);
        float s6 = silu_f(bv1.z + a8[6]), s7 = silu_f(bv1.w + a8[7]);
        uint4 ph;
        ph.x = pk_bf16(s0, s1); ph.y = pk_bf16(s2, s3);
        ph.z = pk_bf16(s4, s5); ph.w = pk_bf16(s6, s7);
        *(uint4*)&fr[0][mtl][ksw][lanef + (c_l & 15)][0] = ph;
    }

    for (int ch = 0; ch < 4; ++ch) {
        const int cur = ch & 1;
        __syncthreads();
        // issue next-chunk global loads early (latency hides under MFMA)
        float nv[2][8];
        if (ch < 3) {
#pragma unroll
            for (int iter = 0; iter < 2; ++iter) {
                const int c_l = iter * 16 + (t >> 4);
                const float* Brow = &Bb[(size_t)(b0 + (ch + 1) * 32 + c_l) * EHD + kg * 8];
                const float4 bv0 = *(const float4*)Brow;
                const float4 bv1 = *(const float4*)(Brow + 4);
                nv[iter][0] = bv0.x; nv[iter][1] = bv0.y; nv[iter][2] = bv0.z; nv[iter][3] = bv0.w;
                nv[iter][4] = bv1.x; nv[iter][5] = bv1.y; nv[iter][6] = bv1.z; nv[iter][7] = bv1.w;
            }
        }
        // MFMA cluster from fr[cur]
        f32x4 acc[2][2];
        __builtin_amdgcn_s_setprio(1);
#pragma unroll
        for (int mtl = 0; mtl < 2; ++mtl) {
            bf16x8 ah[4];
#pragma unroll
            for (int ks = 0; ks < 4; ++ks)
                ah[ks] = *(const bf16x8*)&fr[cur][mtl][ks][lane][0];
#pragma unroll
            for (int nti = 0; nti < 2; ++nti) {
                f32x4 a = {0.0f, 0.0f, 0.0f, 0.0f};
#pragma unroll
                for (int ks = 0; ks < 4; ++ks)
                    a = __builtin_amdgcn_mfma_f32_16x16x32_bf16(ah[ks], bh[nti][ks], a, 0, 0, 0);
                acc[mtl][nti] = a;
            }
        }
        __builtin_amdgcn_s_setprio(0);
        // pack + write next chunk into fr[cur^1]
        if (ch < 3) {
#pragma unroll
            for (int iter = 0; iter < 2; ++iter) {
                const int c_l = iter * 16 + (t >> 4);
                const int mtl = c_l >> 4;
                float s0 = silu_f(nv[iter][0] + a8[0]), s1 = silu_f(nv[iter][1] + a8[1]);
                float s2 = silu_f(nv[iter][2] + a8[2]), s3 = silu_f(nv[iter][3] + a8[3]);
                float s4 = silu_f(nv[iter][4] + a8[4]), s5 = silu_f(nv[iter][5] + a8[5]);
                float s6 = silu_f(nv[iter][6] + a8[6]), s7 = silu_f(nv[iter][7] + a8[7]);
                uint4 ph;
                ph.x = pk_bf16(s0, s1); ph.y = pk_bf16(s2, s3);
                ph.z = pk_bf16(s4, s5); ph.w = pk_bf16(s6, s7);
                *(uint4*)&fr[cur ^ 1][mtl][ksw][lanef + (c_l & 15)][0] = ph;
            }
        }
        // epilogue: silu + masked colsum
#pragma unroll
        for (int mtl = 0; mtl < 2; ++mtl) {
            const int cbase = ch * 32 + mtl * 16 + ((lane >> 4) << 2);
#pragma unroll
            for (int nti = 0; nti < 2; ++nti) {
#pragma unroll
                for (int reg = 0; reg < 4; ++reg) {
                    const int c = cbase + reg;
                    float s = silu_f(acc[mtl][nti][reg] + be2v[nti]);
                    colsum[nti] += (c != r) ? s : 0.0f;
                }
            }
        }
    }
#pragma unroll
    for (int nti = 0; nti < 2; ++nti) {
        float s = colsum[nti];
        s += __shfl_xor(s, 16);
        s += __shfl_xor(s, 32);
        if (lane < 16)
            agg[(size_t)n * EHD + (w * 2 + nti) * 16 + lane] = s;
    }
}

// ================= node MLP + residual + next-layer A/B (or final out), 1024 thr =================
__global__ __launch_bounds__(1024, 4) void k_node_ab(
        const float* __restrict__ agg,
        const float* __restrict__ bn1, const float* __restrict__ bn2,
        const float* __restrict__ be1, const float* __restrict__ b_out,
        const short* __restrict__ hwn1, const short* __restrict__ lwn1,
        const short* __restrict__ hwn2, const short* __restrict__ lwn2,
        const short* __restrict__ hwe1, const short* __restrict__ lwe1,
        const short* __restrict__ hwout, const short* __restrict__ lwout,
        short* __restrict__ xs_hi, short* __restrict__ xs_lo,
        float* __restrict__ A, float* __restrict__ Bb,
        float* __restrict__ outp, int last) {
    __shared__ __align__(16) short cat[2][12][64][8];
    __shared__ __align__(16) short u1[2][8][64][8];
    __shared__ __align__(16) short xn[2][8][64][8];
    const int t = threadIdx.x;
    const int mt = blockIdx.x;
    const int n0 = mt * 16;
    const int w = t >> 6, lane = t & 63;
    const int r0 = (lane >> 4) * 4;

    {
        int s = t;
        int plane = s >> 9, ks = (s >> 6) & 7, ln = s & 63;
        const bf16x8* srcp = (const bf16x8*)(plane ? xs_lo : xs_hi);
        bf16x8 v = srcp[(size_t)(mt * 8 + ks) * 64 + ln];
        *(bf16x8*)&cat[plane][ks][ln][0] = v;
    }
    {
        const int m = t >> 6;
        const int kq = t & 63;
        const int k0 = kq * 2;
        const float2 v2 = *(const float2*)&agg[(size_t)(n0 + m) * EHD + k0];
        unsigned uh0, ul0, uh1, ul1;
        split_tr(v2.x, uh0, ul0);
        split_tr(v2.y, uh1, ul1);
        const int ks = 8 + (k0 >> 5);
        const int lane2 = m + 16 * ((k0 & 31) >> 3);
        const int i0 = k0 & 7;
        *(unsigned*)&cat[0][ks][lane2][i0] = (uh0 >> 16) | uh1;
        *(unsigned*)&cat[1][ks][lane2][i0] = (ul0 >> 16) | ul1;
    }
    __syncthreads();
    f32x4 acc = {0.f, 0.f, 0.f, 0.f};
#pragma unroll
    for (int ks = 0; ks < 12; ++ks) {
        bf16x8 ah = *(const bf16x8*)&cat[0][ks][lane][0];
        bf16x8 al = *(const bf16x8*)&cat[1][ks][lane][0];
        bf16x8 bh = ((const bf16x8*)hwn1)[(w * 12 + ks) * 64 + lane];
        bf16x8 bl = ((const bf16x8*)lwn1)[(w * 12 + ks) * 64 + lane];
        acc = __builtin_amdgcn_mfma_f32_16x16x32_bf16(ah, bh, acc, 0, 0, 0);
        acc = __builtin_amdgcn_mfma_f32_16x16x32_bf16(al, bh, acc, 0, 0, 0);
        acc = __builtin_amdgcn_mfma_f32_16x16x32_bf16(ah, bl, acc, 0, 0, 0);
    }
    const int col = w * 16 + (lane & 15);
    const int ksu = col >> 5, l2b = 16 * ((col & 31) >> 3), i2 = col & 7;
    {
        float bias = bn1[col];
#pragma unroll
        for (int reg = 0; reg < 4; ++reg) {
            float uv = silu_f(acc[reg] + bias);
            unsigned uh, ul;
            split_tr(uv, uh, ul);
            u1[0][ksu][r0 + reg + l2b][i2] = (short)(uh >> 16);
            u1[1][ksu][r0 + reg + l2b][i2] = (short)(ul >> 16);
        }
    }
    __syncthreads();
    f32x4 acc2 = {0.f, 0.f, 0.f, 0.f};
#pragma unroll
    for (int ks = 0; ks < 8; ++ks) {
        bf16x8 ah = *(const bf16x8*)&u1[0][ks][lane][0];
        bf16x8 al = *(const bf16x8*)&u1[1][ks][lane][0];
        bf16x8 bh = ((const bf16x8*)hwn2)[(w * 8 + ks) * 64 + lane];
        bf16x8 bl = ((const bf16x8*)lwn2)[(w * 8 + ks) * 64 + lane];
        acc2 = __builtin_amdgcn_mfma_f32_16x16x32_bf16(ah, bh, acc2, 0, 0, 0);
        acc2 = __builtin_amdgcn_mfma_f32_16x16x32_bf16(al, bh, acc2, 0, 0, 0);
        acc2 = __builtin_amdgcn_mfma_f32_16x16x32_bf16(ah, bl, acc2, 0, 0, 0);
    }
    {
        float bias = bn2[col];
#pragma unroll
        for (int reg = 0; reg < 4; ++reg) {
            int lane2 = r0 + reg + l2b;
            float xold = bfraw2f((unsigned short)cat[0][ksu][lane2][i2])
                       + bfraw2f((unsigned short)cat[1][ksu][lane2][i2]);
            float xv = acc2[reg] + bias + xold;
            unsigned uh, ul;
            split_tr(xv, uh, ul);
            xn[0][ksu][lane2][i2] = (short)(uh >> 16);
            xn[1][ksu][lane2][i2] = (short)(ul >> 16);
        }
    }
    __syncthreads();
    if (!last) {
        {
            int s = t;
            int plane = s >> 9, ks = (s >> 6) & 7, ln = s & 63;
            bf16x8 v = *(const bf16x8*)&xn[plane][ks][ln][0];
            bf16x8* dstp = (bf16x8*)(plane ? xs_lo : xs_hi);
            dstp[(size_t)(mt * 8 + ks) * 64 + ln] = v;
        }
        f32x4 acc3 = {0.f, 0.f, 0.f, 0.f};
#pragma unroll
        for (int ks = 0; ks < 8; ++ks) {
            bf16x8 ah = *(const bf16x8*)&xn[0][ks][lane][0];
            bf16x8 al = *(const bf16x8*)&xn[1][ks][lane][0];
            bf16x8 bh = ((const bf16x8*)hwe1)[(w * 8 + ks) * 64 + lane];
            bf16x8 bl = ((const bf16x8*)lwe1)[(w * 8 + ks) * 64 + lane];
            acc3 = __builtin_amdgcn_mfma_f32_16x16x32_bf16(ah, bh, acc3, 0, 0, 0);
            acc3 = __builtin_amdgcn_mfma_f32_16x16x32_bf16(al, bh, acc3, 0, 0, 0);
            acc3 = __builtin_amdgcn_mfma_f32_16x16x32_bf16(ah, bl, acc3, 0, 0, 0);
        }
        {
            int j = col;
            float bias = (j < 128) ? be1[j] : 0.0f;
            float* dstp = (j < 128) ? A : Bb;
            int jj = j & 127;
#pragma unroll
            for (int reg = 0; reg < 4; ++reg) {
                int node = n0 + r0 + reg;
                dstp[(size_t)node * 128 + jj] = acc3[reg] + bias;
            }
        }
    } else if (w < 4) {
        f32x4 acco = {0.f, 0.f, 0.f, 0.f};
#pragma unroll
        for (int ks = 0; ks < 8; ++ks) {
            bf16x8 ah = *(const bf16x8*)&xn[0][ks][lane][0];
            bf16x8 al = *(const bf16x8*)&xn[1][ks][lane][0];
            bf16x8 bh = ((const bf16x8*)hwout)[(w * 8 + ks) * 64 + lane];
            bf16x8 bl = ((const bf16x8*)lwout)[(w * 8 + ks) * 64 + lane];
            acco = __builtin_amdgcn_mfma_f32_16x16x32_bf16(ah, bh, acco, 0, 0, 0);
            acco = __builtin_amdgcn_mfma_f32_16x16x32_bf16(al, bh, acco, 0, 0, 0);
            acco = __builtin_amdgcn_mfma_f32_16x16x32_bf16(ah, bl, acco, 0, 0, 0);
        }
        float bias = b_out[col];
#pragma unroll
        for (int reg = 0; reg < 4; ++reg) {
            outp[(size_t)(n0 + r0 + reg) * ONF + col] = acco[reg] + bias;
        }
    }
}

extern "C" void kernel_launch(void* const* d_in, const int* in_sizes, int n_in,
                              void* d_out, int out_size, void* d_ws, size_t ws_size,
                              hipStream_t stream) {
    const float* h     = (const float*)d_in[0];
    const float* w_in  = (const float*)d_in[3];
    const float* b_in  = (const float*)d_in[4];
    const float* w_out = (const float*)d_in[5];
    const float* b_out = (const float*)d_in[6];
    const float* we1   = (const float*)d_in[7];
    const float* be1   = (const float*)d_in[8];
    const float* we2   = (const float*)d_in[9];
    const float* be2   = (const float*)d_in[10];
    const float* wn1   = (const float*)d_in[11];
    const float* bn1   = (const float*)d_in[12];
    const float* wn2   = (const float*)d_in[13];
    const float* bn2   = (const float*)d_in[14];

    float* A    = (float*)d_ws;              // 2048*128
    float* Bb   = A + 262144;                // 2048*128
    float* agg  = Bb + 262144;               // 2048*128
    short* xs_hi = (short*)(agg + 262144);   // 2048*256
    short* xs_lo = xs_hi + 524288;
    short* hwin  = xs_lo + 524288;           // 2048*8
    short* lwin  = hwin + 16384;
    short* hwe1  = lwin + 16384;             // 4*8192*8
    short* lwe1  = hwe1 + 262144;
    short* hwn1  = lwe1 + 262144;            // 4*12288*8
    short* lwn1  = hwn1 + 393216;
    short* hwn2  = lwn1 + 393216;            // 4*8192*8
    short* lwn2  = hwn2 + 262144;
    short* hwout = lwn2 + 262144;            // 2048*8
    short* lwout = hwout + 16384;
    short* hwe2  = lwout + 16384;            // 4*2048*8
    float* outp  = (float*)d_out;

    k_prep<<<496, 256, 0, stream>>>(w_in, we1, wn1, wn2, w_out, we2,
        hwin, lwin, hwe1, lwe1, hwn1, lwn1, hwn2, lwn2, hwout, lwout, hwe2);
    k_embed_ab<<<128, 1024, 0, stream>>>(h, b_in, be1, hwin, lwin, hwe1, lwe1,
        xs_hi, xs_lo, A, Bb);
    for (int l = 0; l < NL; ++l) {
        const int last = (l == NL - 1);
        const int lp = last ? 0 : (l + 1);
        k_edge_mfma<<<NTOT, 256, 0, stream>>>(A, Bb,
            hwe2 + (size_t)l * 2048 * 8,
            be2 + l * EHD, agg);
        k_node_ab<<<128, 1024, 0, stream>>>(agg,
            bn1 + l * HD, bn2 + l * HD, be1 + lp * EHD, b_out,
            hwn1 + (size_t)l * 12288 * 8, lwn1 + (size_t)l * 12288 * 8,
            hwn2 + (size_t)l * 8192 * 8, lwn2 + (size_t)l * 8192 * 8,
            hwe1 + (size_t)lp * 8192 * 8, lwe1 + (size_t)lp * 8192 * 8,
            hwout, lwout, xs_hi, xs_lo, A, Bb, outp, last);
    }
}